// Round 8
// baseline (42.470 us; speedup 1.0000x reference)
//
#include <hip/hip_runtime.h>

// AdaCoF sampler: out[b,c,h,w] = sum_k weights[b,k,h,w] * bilinear(image[b,c], y+dy, x+dx)
// B=4, C=3, H=W=256, K2=49.
// R7 post-mortem: LDS widening gave only 10% (35.8us); conflicts ~7.5e6 are
// inherent to divergent gathers (layout near-optimal already). Remaining
// cost = exposed latency: staging phase serial in front, and 1-group-ahead
// prefetch (~350cyc cover) < stream latency (~500-900cyc) at 3.7 waves/SIMD.
// R8: (1) group-0 + tail stream loads hoisted ABOVE halo staging (latency
// hides under staging); (2) triple-buffered stream pipeline (2 groups ahead,
// ~24 loads in flight). LDS gather structure unchanged from R7.

#define BB 4
#define CC 3
#define HH 256
#define WW 256
#define K2 49
#define HWSZ (HH * WW)
#define SCALE (256.0f / 255.0f)

#define ROWS 21          // halo rows: [Y0-8, Y0+12]
#define COLS 81          // halo cols: [X0-8, X0+72]
#define NCELL (ROWS * COLS)   // 1701

__global__ void __launch_bounds__(512)
adacof_tile(const float* __restrict__ img,
            const float* __restrict__ offsets,
            const float* __restrict__ weights,
            float* __restrict__ out) {
    __shared__ float2 t01[NCELL];        // ch0,ch1 packed: 13,608 B
    __shared__ float  t2[NCELL];         // ch2:             6,804 B
    __shared__ float  redbuf[CC][256];   //                  3,072 B

    const int t = threadIdx.x;
    const int h = t >> 8;                // k-half (wave-uniform)
    const int pix = t & 255;
    const int tx = pix & 63;
    const int ty = pix >> 6;             // wave = one 64-px row

    const int bid = blockIdx.x;
    const int b = bid >> 8;
    const int tIdx = bid & 255;
    const int X0 = (tIdx & 3) << 6;      // 4 tile cols of 64
    const int Y0 = (tIdx >> 2) << 2;     // 64 tile rows of 4
    const int OX = X0 - 8, OY = Y0 - 8;

    const float* imgB = img + (size_t)b * (CC * HWSZ);

    const int hw = (Y0 + ty) * WW + X0 + tx;
    const int kbase = h * 24;            // half0: k 0..23 ; half1: k 24..47 + 48
    const float* offH = offsets + (size_t)b * (2 * K2 * HWSZ)
                                + (size_t)(2 * kbase) * HWSZ + hw;
    const float* wgtH = weights + (size_t)b * (K2 * HWSZ)
                                + (size_t)kbase * HWSZ + hw;

    // stream-load group G (4 taps) into buffer slot BUF
    float dxv[3][4], dyv[3][4], wgv[3][4];
#define LOADG(BUF, G) do {                                                   \
    _Pragma("unroll")                                                        \
    for (int j = 0; j < 4; ++j) {                                            \
        int k = 4 * (G) + j;                                                 \
        dxv[BUF][j] = offH[(size_t)(2 * k) * HWSZ];                          \
        dyv[BUF][j] = offH[(size_t)(2 * k + 1) * HWSZ];                      \
        wgv[BUF][j] = wgtH[(size_t)k * HWSZ];                                \
    }                                                                        \
} while (0)

    // ---- issue group 0 + tail streams BEFORE staging: latency hides under it
    LOADG(0, 0);
    float dxt = 0.0f, dyt = 0.0f, wgt = 0.0f;
    if (h == 1) {   // tail tap k=48 (rel planes 48,49; rel weight 24)
        dxt = offH[(size_t)48 * HWSZ];
        dyt = offH[(size_t)49 * HWSZ];
        wgt = wgtH[(size_t)24 * HWSZ];
    }
    __builtin_amdgcn_sched_barrier(0);

    // ---- stage halo: clamped-replicated borders ----
    {
        const float* p0 = imgB;
        const float* p1 = imgB + HWSZ;
        const float* p2 = imgB + 2 * HWSZ;
        for (int i = t; i < NCELL; i += 512) {
            int ry = i / COLS;
            int rx = i - ry * COLS;
            int gy = min(max(OY + ry, 0), HH - 1);
            int gx = min(max(OX + rx, 0), WW - 1);
            int gi = gy * WW + gx;
            t01[i] = make_float2(p0[gi], p1[gi]);
            t2[i] = p2[gi];
        }
    }
    __syncthreads();

    // ---- second prefetch group while first group's waitcnt drains ----
    LOADG(1, 1);
    __builtin_amdgcn_sched_barrier(0);

    // tile-frame sampling constants. With border replication, un-clamped
    // halo sampling == reference's image-clamped sampling whenever
    // |dx|,|dy| <= 7 (then px in [0.47,78.6], py in [0.47,19.6]).
    const float Axt = (float)(X0 + tx) * SCALE - 0.5f - (float)OX;
    const float Ayt = (float)(Y0 + ty) * SCALE - 0.5f - (float)OY;

    float acc0 = 0.0f, acc1 = 0.0f, acc2 = 0.0f;
    int badm = 0;

    auto TAP = [&](float dx, float dy, float wg) {
        badm |= (fabsf(dx) > 7.0f) | (fabsf(dy) > 7.0f);
        float px = fmaf(dx, SCALE, Axt);
        float py = fmaf(dy, SCALE, Ayt);
        px = fminf(fmaxf(px, 0.0f), 79.0f);   // defensive only (badm covers correctness)
        py = fminf(fmaxf(py, 0.0f), 19.0f);
        float x0f = floorf(px), y0f = floorf(py);
        float wx = px - x0f, wy = py - y0f;
        int i00 = (int)y0f * COLS + (int)x0f;
        float a11 = wx * wy;
        float a10 = wy - a11;
        float a01 = wx - a11;
        float a00 = (1.0f - wx) - a10;
        a00 *= wg; a01 *= wg; a10 *= wg; a11 *= wg;
        float2 c00 = t01[i00];
        float2 c01 = t01[i00 + 1];
        float2 c10 = t01[i00 + COLS];
        float2 c11 = t01[i00 + COLS + 1];
        float d00 = t2[i00];
        float d01 = t2[i00 + 1];
        float d10 = t2[i00 + COLS];
        float d11 = t2[i00 + COLS + 1];
        acc0 = fmaf(c00.x, a00, fmaf(c01.x, a01, fmaf(c10.x, a10, fmaf(c11.x, a11, acc0))));
        acc1 = fmaf(c00.y, a00, fmaf(c01.y, a01, fmaf(c10.y, a10, fmaf(c11.y, a11, acc1))));
        acc2 = fmaf(d00, a00, fmaf(d01, a01, fmaf(d10, a10, fmaf(d11, a11, acc2))));
    };

    // ---- pipeline: 6 groups of 4 taps, prefetch TWO groups ahead ----
    #pragma unroll
    for (int g = 0; g < 6; ++g) {
        if (g + 2 < 6) LOADG((g + 2) % 3, g + 2);
        __builtin_amdgcn_sched_barrier(0);   // prefetch issues before this group's compute
        #pragma unroll
        for (int j = 0; j < 4; ++j)
            TAP(dxv[g % 3][j], dyv[g % 3][j], wgv[g % 3][j]);
    }
    if (h == 1) TAP(dxt, dyt, wgt);

    // ---- cold correctness backstop (offsets ~N(0,1): never taken) ----
    if (__any(badm)) {
        if (badm) {
            const float Axi = (float)(X0 + tx) * SCALE - 0.5f;
            const float Ayi = (float)(Y0 + ty) * SCALE - 0.5f;
            float a0 = 0.0f, a1 = 0.0f, a2 = 0.0f;
            int ntap = (h == 1) ? 25 : 24;
            for (int idx = 0; idx < ntap; ++idx) {
                int k = (idx == 24) ? 48 : (kbase + idx);
                float dx = offsets[(size_t)b * (2 * K2 * HWSZ) + (size_t)(2 * k) * HWSZ + hw];
                float dy = offsets[(size_t)b * (2 * K2 * HWSZ) + (size_t)(2 * k + 1) * HWSZ + hw];
                float wg = weights[(size_t)b * (K2 * HWSZ) + (size_t)k * HWSZ + hw];
                float px = fminf(fmaxf(fmaf(dx, SCALE, Axi), 0.0f), 255.0f);
                float py = fminf(fmaxf(fmaf(dy, SCALE, Ayi), 0.0f), 255.0f);
                float x0f = floorf(px), y0f = floorf(py);
                float wx = px - x0f, wy = py - y0f;
                int ix0 = (int)x0f, iy0 = (int)y0f;
                int ix1 = min(ix0 + 1, WW - 1), iy1 = min(iy0 + 1, HH - 1);
                float w11 = wx * wy, w10 = wy - w11, w01 = wx - w11;
                float w00 = (1.0f - wx) - w10;
                #pragma unroll
                for (int c = 0; c < CC; ++c) {
                    const float* p = imgB + (size_t)c * HWSZ;
                    float bil = p[iy0 * WW + ix0] * w00 + p[iy0 * WW + ix1] * w01
                              + p[iy1 * WW + ix0] * w10 + p[iy1 * WW + ix1] * w11;
                    if (c == 0) a0 = fmaf(wg, bil, a0);
                    else if (c == 1) a1 = fmaf(wg, bil, a1);
                    else a2 = fmaf(wg, bil, a2);
                }
            }
            acc0 = a0; acc1 = a1; acc2 = a2;
        }
    }

    // ---- combine halves, write out ----
    if (h == 1) {
        redbuf[0][pix] = acc0;
        redbuf[1][pix] = acc1;
        redbuf[2][pix] = acc2;
    }
    __syncthreads();
    if (h == 0) {
        acc0 += redbuf[0][pix];
        acc1 += redbuf[1][pix];
        acc2 += redbuf[2][pix];
        float* o = out + (size_t)b * (CC * HWSZ) + hw;
        o[0] = acc0;
        o[HWSZ] = acc1;
        o[2 * HWSZ] = acc2;
    }
#undef LOADG
}

extern "C" void kernel_launch(void* const* d_in, const int* in_sizes, int n_in,
                              void* d_out, int out_size, void* d_ws, size_t ws_size,
                              hipStream_t stream) {
    const float* image = (const float*)d_in[0];
    const float* offsets = (const float*)d_in[1];
    const float* weights = (const float*)d_in[2];
    float* out = (float*)d_out;

    // 4 batches x 256 tiles (64x4 px); 512 threads = 256 px x 2 k-halves
    adacof_tile<<<BB * 256, 512, 0, stream>>>(image, offsets, weights, out);
}

// Round 9
// 33.500 us; speedup vs baseline: 1.2678x; 1.2678x over previous
//
#include <hip/hip_runtime.h>

// AdaCoF sampler: out[b,c,h,w] = sum_k weights[b,k,h,w] * bilinear(image[b,c], y+dy, x+dx)
// B=4, C=3, H=W=256, K2=49.
// R8 post-mortem: triple-buffer pushed VGPR 40->72, crossed the 64-VGPR
// occupancy cliff (46%->20%) -> regression. Reverted to R7 pipeline.
// R9: LDS cell = all 3 channels packed bf16 in 8B (uint2). Per tap:
//   vaddr=i00 -> ds_read2_b64 off{0,1} + ds_read2_b64 off{81,82}
//   = 2 LDS instrs, 4 accesses, 32B (R7: 4 instrs, 8 accesses, 48B).
// Conflict cycles ~halve; one shared addr calc per tap. Unpack = <<16 /
// &0xFFFF0000 per channel. bf16 image error ~0.2 max << 0.94 threshold.
// Backstop (badm -> full-f32 global recompute) keeps exactness for any
// offset magnitude.

#define BB 4
#define CC 3
#define HH 256
#define WW 256
#define K2 49
#define HWSZ (HH * WW)
#define SCALE (256.0f / 255.0f)

#define ROWS 21          // halo rows: [Y0-8, Y0+12]
#define COLS 81          // halo cols: [X0-8, X0+72]
#define NCELL (ROWS * COLS)   // 1701

__device__ __forceinline__ unsigned bf16_rne(float f) {
    unsigned u = __float_as_uint(f);
    return (u + 0x7FFFu + ((u >> 16) & 1u)) >> 16;   // round-nearest-even
}

__global__ void __launch_bounds__(512)
adacof_tile(const float* __restrict__ img,
            const float* __restrict__ offsets,
            const float* __restrict__ weights,
            float* __restrict__ out) {
    __shared__ uint2 tp[NCELL];          // bf16 ch0|ch1, bf16 ch2: 13,608 B
    __shared__ float redbuf[CC][256];    //                          3,072 B

    const int t = threadIdx.x;
    const int h = t >> 8;                // k-half (wave-uniform)
    const int pix = t & 255;
    const int tx = pix & 63;
    const int ty = pix >> 6;             // wave = one 64-px row

    const int bid = blockIdx.x;
    const int b = bid >> 8;
    const int tIdx = bid & 255;
    const int X0 = (tIdx & 3) << 6;      // 4 tile cols of 64
    const int Y0 = (tIdx >> 2) << 2;     // 64 tile rows of 4
    const int OX = X0 - 8, OY = Y0 - 8;

    const float* imgB = img + (size_t)b * (CC * HWSZ);

    // ---- stage halo: clamped-replicated borders, bf16-packed ----
    {
        const float* p0 = imgB;
        const float* p1 = imgB + HWSZ;
        const float* p2 = imgB + 2 * HWSZ;
        for (int i = t; i < NCELL; i += 512) {
            int ry = i / COLS;
            int rx = i - ry * COLS;
            int gy = min(max(OY + ry, 0), HH - 1);
            int gx = min(max(OX + rx, 0), WW - 1);
            int gi = gy * WW + gx;
            uint2 cell;
            cell.x = bf16_rne(p0[gi]) | (bf16_rne(p1[gi]) << 16);
            cell.y = bf16_rne(p2[gi]);
            tp[i] = cell;
        }
    }
    __syncthreads();

    const int hw = (Y0 + ty) * WW + X0 + tx;
    const int kbase = h * 24;            // half0: k 0..23 ; half1: k 24..47 + 48
    const float* offH = offsets + (size_t)b * (2 * K2 * HWSZ)
                                + (size_t)(2 * kbase) * HWSZ + hw;
    const float* wgtH = weights + (size_t)b * (K2 * HWSZ)
                                + (size_t)kbase * HWSZ + hw;

    // tile-frame sampling constants. With border replication, un-clamped
    // halo sampling == reference's image-clamped sampling whenever
    // |dx|,|dy| <= 7 (then px in [0.47,78.6], py in [0.47,19.6]).
    const float Axt = (float)(X0 + tx) * SCALE - 0.5f - (float)OX;
    const float Ayt = (float)(Y0 + ty) * SCALE - 0.5f - (float)OY;

    float acc0 = 0.0f, acc1 = 0.0f, acc2 = 0.0f;
    int badm = 0;

    auto TAP = [&](float dx, float dy, float wg) {
        badm |= (fabsf(dx) > 7.0f) | (fabsf(dy) > 7.0f);
        float px = fmaf(dx, SCALE, Axt);
        float py = fmaf(dy, SCALE, Ayt);
        px = fminf(fmaxf(px, 0.0f), 79.0f);   // defensive (badm covers correctness)
        py = fminf(fmaxf(py, 0.0f), 19.0f);
        float x0f = floorf(px), y0f = floorf(py);
        float wx = px - x0f, wy = py - y0f;
        int i00 = (int)y0f * COLS + (int)x0f;
        float a11 = wx * wy;
        float a10 = wy - a11;
        float a01 = wx - a11;
        float a00 = (1.0f - wx) - a10;
        a00 *= wg; a01 *= wg; a10 *= wg; a11 *= wg;
        // 2x ds_read2_b64 from one base: {0,1} and {81,82}
        uint2 q00 = tp[i00];
        uint2 q01 = tp[i00 + 1];
        uint2 q10 = tp[i00 + COLS];
        uint2 q11 = tp[i00 + COLS + 1];
        acc0 = fmaf(__uint_as_float(q00.x << 16), a00,
               fmaf(__uint_as_float(q01.x << 16), a01,
               fmaf(__uint_as_float(q10.x << 16), a10,
               fmaf(__uint_as_float(q11.x << 16), a11, acc0))));
        acc1 = fmaf(__uint_as_float(q00.x & 0xFFFF0000u), a00,
               fmaf(__uint_as_float(q01.x & 0xFFFF0000u), a01,
               fmaf(__uint_as_float(q10.x & 0xFFFF0000u), a10,
               fmaf(__uint_as_float(q11.x & 0xFFFF0000u), a11, acc1))));
        acc2 = fmaf(__uint_as_float(q00.y << 16), a00,
               fmaf(__uint_as_float(q01.y << 16), a01,
               fmaf(__uint_as_float(q10.y << 16), a10,
               fmaf(__uint_as_float(q11.y << 16), a11, acc2))));
    };

    // ---- stream pipeline: 6 groups of 4 taps, prefetch one group ahead ----
    float dxv[2][4], dyv[2][4], wgv[2][4];
    #pragma unroll
    for (int j = 0; j < 4; ++j) {
        dxv[0][j] = offH[(size_t)(2 * j) * HWSZ];
        dyv[0][j] = offH[(size_t)(2 * j + 1) * HWSZ];
        wgv[0][j] = wgtH[(size_t)j * HWSZ];
    }
    float dxt = 0.0f, dyt = 0.0f, wgt = 0.0f;
    if (h == 1) {   // tail tap k=48 (rel planes 48,49; rel weight 24)
        dxt = offH[(size_t)48 * HWSZ];
        dyt = offH[(size_t)49 * HWSZ];
        wgt = wgtH[(size_t)24 * HWSZ];
    }
    __builtin_amdgcn_sched_barrier(0);

    #pragma unroll
    for (int g = 0; g < 6; ++g) {
        if (g < 5) {
            #pragma unroll
            for (int j = 0; j < 4; ++j) {
                int k = 4 * (g + 1) + j;
                dxv[(g + 1) & 1][j] = offH[(size_t)(2 * k) * HWSZ];
                dyv[(g + 1) & 1][j] = offH[(size_t)(2 * k + 1) * HWSZ];
                wgv[(g + 1) & 1][j] = wgtH[(size_t)k * HWSZ];
            }
        }
        __builtin_amdgcn_sched_barrier(0);   // loads issue before this group's compute
        #pragma unroll
        for (int j = 0; j < 4; ++j)
            TAP(dxv[g & 1][j], dyv[g & 1][j], wgv[g & 1][j]);
    }
    if (h == 1) TAP(dxt, dyt, wgt);

    // ---- cold correctness backstop (offsets ~N(0,1): never taken) ----
    if (__any(badm)) {
        if (badm) {
            const float Axi = (float)(X0 + tx) * SCALE - 0.5f;
            const float Ayi = (float)(Y0 + ty) * SCALE - 0.5f;
            float a0 = 0.0f, a1 = 0.0f, a2 = 0.0f;
            int ntap = (h == 1) ? 25 : 24;
            for (int idx = 0; idx < ntap; ++idx) {
                int k = (idx == 24) ? 48 : (kbase + idx);
                float dx = offsets[(size_t)b * (2 * K2 * HWSZ) + (size_t)(2 * k) * HWSZ + hw];
                float dy = offsets[(size_t)b * (2 * K2 * HWSZ) + (size_t)(2 * k + 1) * HWSZ + hw];
                float wg = weights[(size_t)b * (K2 * HWSZ) + (size_t)k * HWSZ + hw];
                float px = fminf(fmaxf(fmaf(dx, SCALE, Axi), 0.0f), 255.0f);
                float py = fminf(fmaxf(fmaf(dy, SCALE, Ayi), 0.0f), 255.0f);
                float x0f = floorf(px), y0f = floorf(py);
                float wx = px - x0f, wy = py - y0f;
                int ix0 = (int)x0f, iy0 = (int)y0f;
                int ix1 = min(ix0 + 1, WW - 1), iy1 = min(iy0 + 1, HH - 1);
                float w11 = wx * wy, w10 = wy - w11, w01 = wx - w11;
                float w00 = (1.0f - wx) - w10;
                #pragma unroll
                for (int c = 0; c < CC; ++c) {
                    const float* p = imgB + (size_t)c * HWSZ;
                    float bil = p[iy0 * WW + ix0] * w00 + p[iy0 * WW + ix1] * w01
                              + p[iy1 * WW + ix0] * w10 + p[iy1 * WW + ix1] * w11;
                    if (c == 0) a0 = fmaf(wg, bil, a0);
                    else if (c == 1) a1 = fmaf(wg, bil, a1);
                    else a2 = fmaf(wg, bil, a2);
                }
            }
            acc0 = a0; acc1 = a1; acc2 = a2;
        }
    }

    // ---- combine halves, write out ----
    if (h == 1) {
        redbuf[0][pix] = acc0;
        redbuf[1][pix] = acc1;
        redbuf[2][pix] = acc2;
    }
    __syncthreads();
    if (h == 0) {
        acc0 += redbuf[0][pix];
        acc1 += redbuf[1][pix];
        acc2 += redbuf[2][pix];
        float* o = out + (size_t)b * (CC * HWSZ) + hw;
        o[0] = acc0;
        o[HWSZ] = acc1;
        o[2 * HWSZ] = acc2;
    }
}

extern "C" void kernel_launch(void* const* d_in, const int* in_sizes, int n_in,
                              void* d_out, int out_size, void* d_ws, size_t ws_size,
                              hipStream_t stream) {
    const float* image = (const float*)d_in[0];
    const float* offsets = (const float*)d_in[1];
    const float* weights = (const float*)d_in[2];
    float* out = (float*)d_out;

    // 4 batches x 256 tiles (64x4 px); 512 threads = 256 px x 2 k-halves
    adacof_tile<<<BB * 256, 512, 0, stream>>>(image, offsets, weights, out);
}

// Round 10
// 32.541 us; speedup vs baseline: 1.3051x; 1.0295x over previous
//
#include <hip/hip_runtime.h>
#include <hip/hip_fp16.h>

// AdaCoF sampler: out[b,c,h,w] = sum_k weights[b,k,h,w] * bilinear(image[b,c], y+dy, x+dx)
// B=4, C=3, H=W=256, K2=49.
// R9 post-mortem: conflicts halved as predicted (7.5e6->4.6e6) but only
// -2.3us; VALU is now the largest component (~14us: ~49 ops/tap incl. 12
// unpack + 12 scalar fma). LDS ~11-12us, streams ~13us.
// R10: packed-fp16 math, same memory structure:
//  - cell = half2{ch0,ch1} + half2{ch2,0} (8B, same 2x ds_read2_b64)
//  - 8x v_pk_fma_f16 per tap (__hfma2) replaces 12 unpack + 12 fma;
//    weights packed via 4x v_cvt_pkrtz (__floats2half2_rn)
//  - half2 accumulation flushed to f32 every 4-tap group (error ~0.01/group)
//  - v_med3_f32 clamps (1 instr), fused max3 badm (1 instr/tap)
// fp16 image quant (5e-4) beats bf16 (4e-3): absmax should DROP.

#define BB 4
#define CC 3
#define HH 256
#define WW 256
#define K2 49
#define HWSZ (HH * WW)
#define SCALE (256.0f / 255.0f)

#define ROWS 21          // halo rows: [Y0-8, Y0+12]
#define COLS 81          // halo cols: [X0-8, X0+72]
#define NCELL (ROWS * COLS)   // 1701

struct alignas(8) Cell { __half2 a, b; };   // a = {ch0,ch1}, b = {ch2, 0}

__global__ void __launch_bounds__(512)
adacof_tile(const float* __restrict__ img,
            const float* __restrict__ offsets,
            const float* __restrict__ weights,
            float* __restrict__ out) {
    __shared__ Cell tp[NCELL];           // 13,608 B
    __shared__ float redbuf[CC][256];    //  3,072 B

    const int t = threadIdx.x;
    const int h = t >> 8;                // k-half (wave-uniform)
    const int pix = t & 255;
    const int tx = pix & 63;
    const int ty = pix >> 6;             // wave = one 64-px row

    const int bid = blockIdx.x;
    const int b = bid >> 8;
    const int tIdx = bid & 255;
    const int X0 = (tIdx & 3) << 6;      // 4 tile cols of 64
    const int Y0 = (tIdx >> 2) << 2;     // 64 tile rows of 4
    const int OX = X0 - 8, OY = Y0 - 8;

    const float* imgB = img + (size_t)b * (CC * HWSZ);

    // ---- stage halo: clamped-replicated borders, fp16-packed ----
    {
        const float* p0 = imgB;
        const float* p1 = imgB + HWSZ;
        const float* p2 = imgB + 2 * HWSZ;
        for (int i = t; i < NCELL; i += 512) {
            int ry = i / COLS;
            int rx = i - ry * COLS;
            int gy = min(max(OY + ry, 0), HH - 1);
            int gx = min(max(OX + rx, 0), WW - 1);
            int gi = gy * WW + gx;
            Cell cell;
            cell.a = __floats2half2_rn(p0[gi], p1[gi]);
            cell.b = __floats2half2_rn(p2[gi], 0.0f);
            tp[i] = cell;
        }
    }
    __syncthreads();

    const int hw = (Y0 + ty) * WW + X0 + tx;
    const int kbase = h * 24;            // half0: k 0..23 ; half1: k 24..47 + 48
    const float* offH = offsets + (size_t)b * (2 * K2 * HWSZ)
                                + (size_t)(2 * kbase) * HWSZ + hw;
    const float* wgtH = weights + (size_t)b * (K2 * HWSZ)
                                + (size_t)kbase * HWSZ + hw;

    // tile-frame sampling constants. Border replication == reference clamp
    // whenever |dx|,|dy| <= 7.
    const float Axt = (float)(X0 + tx) * SCALE - 0.5f - (float)OX;
    const float Ayt = (float)(Y0 + ty) * SCALE - 0.5f - (float)OY;

    float acc0 = 0.0f, acc1 = 0.0f, acc2 = 0.0f;
    float badv = 0.0f;
    __half2 acc01h = __floats2half2_rn(0.0f, 0.0f);
    __half2 acc2h = acc01h;

    auto TAP = [&](float dx, float dy, float wg) {
        badv = fmaxf(fmaxf(fabsf(dx), fabsf(dy)), badv);   // v_max3 w/ abs mods
        float px = fmaf(dx, SCALE, Axt);
        float py = fmaf(dy, SCALE, Ayt);
        px = __builtin_amdgcn_fmed3f(px, 0.0f, 79.0f);     // halo clamp, 1 instr
        py = __builtin_amdgcn_fmed3f(py, 0.0f, 19.0f);
        float x0f = floorf(px), y0f = floorf(py);
        float wx = px - x0f, wy = py - y0f;
        int i00 = (int)fmaf(y0f, (float)COLS, x0f);
        float a11 = wx * wy;
        float a10 = wy - a11;
        float a01 = wx - a11;
        float a00 = (1.0f - wx) - a10;
        a00 *= wg; a01 *= wg; a10 *= wg; a11 *= wg;
        __half2 W00 = __floats2half2_rn(a00, a00);
        __half2 W01 = __floats2half2_rn(a01, a01);
        __half2 W10 = __floats2half2_rn(a10, a10);
        __half2 W11 = __floats2half2_rn(a11, a11);
        Cell q00 = tp[i00];
        Cell q01 = tp[i00 + 1];
        Cell q10 = tp[i00 + COLS];
        Cell q11 = tp[i00 + COLS + 1];
        acc01h = __hfma2(q00.a, W00, acc01h);
        acc2h  = __hfma2(q00.b, W00, acc2h);
        acc01h = __hfma2(q01.a, W01, acc01h);
        acc2h  = __hfma2(q01.b, W01, acc2h);
        acc01h = __hfma2(q10.a, W10, acc01h);
        acc2h  = __hfma2(q10.b, W10, acc2h);
        acc01h = __hfma2(q11.a, W11, acc01h);
        acc2h  = __hfma2(q11.b, W11, acc2h);
    };

    auto FLUSH = [&]() {
        float2 f01 = __half22float2(acc01h);
        float2 f2 = __half22float2(acc2h);
        acc0 += f01.x;
        acc1 += f01.y;
        acc2 += f2.x;
        acc01h = __floats2half2_rn(0.0f, 0.0f);
        acc2h = acc01h;
    };

    // ---- stream pipeline: 6 groups of 4 taps, prefetch one group ahead ----
    float dxv[2][4], dyv[2][4], wgv[2][4];
    #pragma unroll
    for (int j = 0; j < 4; ++j) {
        dxv[0][j] = offH[(size_t)(2 * j) * HWSZ];
        dyv[0][j] = offH[(size_t)(2 * j + 1) * HWSZ];
        wgv[0][j] = wgtH[(size_t)j * HWSZ];
    }
    float dxt = 0.0f, dyt = 0.0f, wgt = 0.0f;
    if (h == 1) {   // tail tap k=48 (rel planes 48,49; rel weight 24)
        dxt = offH[(size_t)48 * HWSZ];
        dyt = offH[(size_t)49 * HWSZ];
        wgt = wgtH[(size_t)24 * HWSZ];
    }
    __builtin_amdgcn_sched_barrier(0);

    #pragma unroll
    for (int g = 0; g < 6; ++g) {
        if (g < 5) {
            #pragma unroll
            for (int j = 0; j < 4; ++j) {
                int k = 4 * (g + 1) + j;
                dxv[(g + 1) & 1][j] = offH[(size_t)(2 * k) * HWSZ];
                dyv[(g + 1) & 1][j] = offH[(size_t)(2 * k + 1) * HWSZ];
                wgv[(g + 1) & 1][j] = wgtH[(size_t)k * HWSZ];
            }
        }
        __builtin_amdgcn_sched_barrier(0);   // loads issue before this group's compute
        #pragma unroll
        for (int j = 0; j < 4; ++j)
            TAP(dxv[g & 1][j], dyv[g & 1][j], wgv[g & 1][j]);
        FLUSH();                             // bound fp16 accumulation error
    }
    if (h == 1) {
        TAP(dxt, dyt, wgt);
        FLUSH();
    }

    // ---- cold correctness backstop (offsets ~N(0,1): never taken) ----
    if (__any(badv > 7.0f)) {
        if (badv > 7.0f) {
            const float Axi = (float)(X0 + tx) * SCALE - 0.5f;
            const float Ayi = (float)(Y0 + ty) * SCALE - 0.5f;
            float a0 = 0.0f, a1 = 0.0f, a2 = 0.0f;
            int ntap = (h == 1) ? 25 : 24;
            for (int idx = 0; idx < ntap; ++idx) {
                int k = (idx == 24) ? 48 : (kbase + idx);
                float dx = offsets[(size_t)b * (2 * K2 * HWSZ) + (size_t)(2 * k) * HWSZ + hw];
                float dy = offsets[(size_t)b * (2 * K2 * HWSZ) + (size_t)(2 * k + 1) * HWSZ + hw];
                float wg = weights[(size_t)b * (K2 * HWSZ) + (size_t)k * HWSZ + hw];
                float px = fminf(fmaxf(fmaf(dx, SCALE, Axi), 0.0f), 255.0f);
                float py = fminf(fmaxf(fmaf(dy, SCALE, Ayi), 0.0f), 255.0f);
                float x0f = floorf(px), y0f = floorf(py);
                float wx = px - x0f, wy = py - y0f;
                int ix0 = (int)x0f, iy0 = (int)y0f;
                int ix1 = min(ix0 + 1, WW - 1), iy1 = min(iy0 + 1, HH - 1);
                float w11 = wx * wy, w10 = wy - w11, w01 = wx - w11;
                float w00 = (1.0f - wx) - w10;
                #pragma unroll
                for (int c = 0; c < CC; ++c) {
                    const float* p = imgB + (size_t)c * HWSZ;
                    float bil = p[iy0 * WW + ix0] * w00 + p[iy0 * WW + ix1] * w01
                              + p[iy1 * WW + ix0] * w10 + p[iy1 * WW + ix1] * w11;
                    if (c == 0) a0 = fmaf(wg, bil, a0);
                    else if (c == 1) a1 = fmaf(wg, bil, a1);
                    else a2 = fmaf(wg, bil, a2);
                }
            }
            acc0 = a0; acc1 = a1; acc2 = a2;
        }
    }

    // ---- combine halves, write out ----
    if (h == 1) {
        redbuf[0][pix] = acc0;
        redbuf[1][pix] = acc1;
        redbuf[2][pix] = acc2;
    }
    __syncthreads();
    if (h == 0) {
        acc0 += redbuf[0][pix];
        acc1 += redbuf[1][pix];
        acc2 += redbuf[2][pix];
        float* o = out + (size_t)b * (CC * HWSZ) + hw;
        o[0] = acc0;
        o[HWSZ] = acc1;
        o[2 * HWSZ] = acc2;
    }
}

extern "C" void kernel_launch(void* const* d_in, const int* in_sizes, int n_in,
                              void* d_out, int out_size, void* d_ws, size_t ws_size,
                              hipStream_t stream) {
    const float* image = (const float*)d_in[0];
    const float* offsets = (const float*)d_in[1];
    const float* weights = (const float*)d_in[2];
    float* out = (float*)d_out;

    // 4 batches x 256 tiles (64x4 px); 512 threads = 256 px x 2 k-halves
    adacof_tile<<<BB * 256, 512, 0, stream>>>(image, offsets, weights, out);
}